// Round 7
// baseline (73.211 us; speedup 1.0000x reference)
//
#include <hip/hip_runtime.h>
#include <hip/hip_bf16.h>
#include <math.h>

#define H 256
#define L_SEQ 131072
#define NBLK 1024           // attention blocks (power of two)
#define RPB (L_SEQ / NBLK)  // 128 rows per block

typedef __attribute__((ext_vector_type(4))) float f32x4;

__device__ __forceinline__ float wave_reduce_sum(float v) {
#pragma unroll
  for (int off = 32; off > 0; off >>= 1) v += __shfl_xor(v, off, 64);
  return v;
}

// One fused kernel: 1024 blocks scan E with online exp-sum attention;
// blocks 0..255 also compute ghh2 = W_hh@h + b + W_ih[:,0:40]@emb and
// transpose W_ih[:,40:50]; blocks 256..271 warm L3 with head weights.
// The LAST block to finish (atomic vote, mod-1024 so no counter reset
// needed) runs the entire tail: combine -> ctx10 -> gates -> LSTM -> heads.
__global__ __launch_bounds__(256, 4) void k1_fused(
    const float* __restrict__ E, const float* __restrict__ h,
    const float* __restrict__ attn_W, const float* __restrict__ W_hh,
    const float* __restrict__ b_ih, const float* __restrict__ b_hh,
    const float* __restrict__ W_ih,
    const float* __restrict__ chord_emb, const float* __restrict__ pitch_emb,
    const float* __restrict__ dur_emb,
    const int* __restrict__ sec_p, const int* __restrict__ chord_p,
    const int* __restrict__ tp_p, const int* __restrict__ note_p,
    const float* __restrict__ attn_b, const float* __restrict__ c_in,
    const float* __restrict__ pitch_W, const float* __restrict__ pitch_b,
    const float* __restrict__ dur_W, const float* __restrict__ dur_b,
    float* __restrict__ p10, float* __restrict__ ghh2,
    float* __restrict__ WcT, float* __restrict__ dummy,
    unsigned* __restrict__ cnt, float* __restrict__ out) {
  const int b = blockIdx.x;
  const int t = threadIdx.x;
  const int lane = t & 63;
  const int w = t >> 6;
  const float4 hreg = reinterpret_cast<const float4*>(h)[lane];

  // ---- attention chunk: fixed M=0 exp-sum, 8-row unroll, non-temporal ----
  float s = 0.f;
  float4 acc = make_float4(0.f, 0.f, 0.f, 0.f);
  const f32x4* E4 = reinterpret_cast<const f32x4*>(E);
  const size_t base = (size_t)b * RPB;
#pragma unroll
  for (int k = 0; k < RPB / 32; ++k) {
    const int r = w * 8 + 32 * k;
    f32x4 e[8];
#pragma unroll
    for (int j = 0; j < 8; ++j)
      e[j] = __builtin_nontemporal_load(&E4[(base + r + j) * 64 + lane]);
    float d[8];
#pragma unroll
    for (int j = 0; j < 8; ++j)
      d[j] = e[j].x * hreg.x + e[j].y * hreg.y + e[j].z * hreg.z + e[j].w * hreg.w;
#pragma unroll
    for (int off = 32; off > 0; off >>= 1) {
#pragma unroll
      for (int j = 0; j < 8; ++j) d[j] += __shfl_xor(d[j], off, 64);
    }
#pragma unroll
    for (int j = 0; j < 8; ++j) {
      const float wj = __expf(d[j]);
      s += wj;
      acc.x += wj * e[j].x;
      acc.y += wj * e[j].y;
      acc.z += wj * e[j].z;
      acc.w += wj * e[j].w;
    }
  }
  __shared__ float ss[4];
  __shared__ float4 sacc4[4][64];
  sacc4[w][lane] = acc;
  if (lane == 0) ss[w] = s;
  __syncthreads();
  __shared__ float ctx_s[H];
  {
    const float* sf = reinterpret_cast<const float*>(sacc4);
    ctx_s[t] = (sf[t] + sf[256 + t]) + (sf[512 + t] + sf[768 + t]);
  }
  __syncthreads();
  {
    const float4 c4 = reinterpret_cast<const float4*>(ctx_s)[lane];
    for (int row = w; row < 10; row += 4) {
      const float4 a4 = reinterpret_cast<const float4*>(attn_W + row * H)[lane];
      float d = c4.x * a4.x + c4.y * a4.y + c4.z * a4.z + c4.w * a4.w;
      d = wave_reduce_sum(d);
      if (lane == 0) p10[row * NBLK + b] = d;
    }
  }
  if (t == 0) p10[10 * NBLK + b] = (ss[0] + ss[1]) + (ss[2] + ss[3]);

  // ---- side work ----
  if (b < 256) {
    const int r = b * 4 + w;  // gate row
    const float4 wv = reinterpret_cast<const float4*>(W_hh + (size_t)r * H)[lane];
    float d = wv.x * hreg.x + wv.y * hreg.y + wv.z * hreg.z + wv.w * hreg.w;
    if (lane < 50) {
      const float wih = W_ih[r * 50 + lane];
      if (lane < 40) {
        int idx; const float* tbl;
        if (lane < 10)      { tbl = pitch_emb; idx = note_p[0] * 10 + lane; }
        else if (lane < 20) { tbl = dur_emb;   idx = note_p[1] * 10 + lane - 10; }
        else if (lane < 30) { tbl = chord_emb; idx = chord_p[0] * 10 + lane - 20; }
        else                { tbl = chord_emb; idx = sec_p[0] * 10 + lane - 30; }
        d += wih * tbl[idx];
      } else {
        WcT[(lane - 40) * NBLK + r] = wih;  // transpose cols 40..49
      }
    }
    d = wave_reduce_sum(d);
    if (lane == 0) ghh2[r] = d + b_ih[r] + b_hh[r];
  } else if (b < 272) {
    const int slice = b - 256;  // warm L3 for the tail
    float a = 0.f;
    const float4* pw4 = reinterpret_cast<const float4*>(pitch_W);
    for (int i = slice * 256 + t; i < 4032; i += 16 * 256) {
      float4 v = pw4[i]; a += v.x + v.y + v.z + v.w;
    }
    const float4* dw4 = reinterpret_cast<const float4*>(dur_W);
    for (int i = slice * 256 + t; i < 1064; i += 16 * 256) {
      float4 v = dw4[i]; a += v.x + v.y + v.z + v.w;
    }
    a = wave_reduce_sum(a);
    if (lane == 0) dummy[slice * 4 + w] = a;
  }

  // ---- completion vote: exactly one winner per call, any counter start ----
  __syncthreads();
  __shared__ unsigned oldsh;
  if (t == 0) {
    __threadfence();  // release: make this block's ws stores visible
    oldsh = __hip_atomic_fetch_add(cnt, 1u, __ATOMIC_ACQ_REL,
                                   __HIP_MEMORY_SCOPE_AGENT);
  }
  __syncthreads();
  if ((oldsh & (NBLK - 1u)) != (NBLK - 1u)) return;
  if (t == 0) __threadfence();  // acquire: see all other blocks' stores
  __syncthreads();

  // ---- tail (winner block only, 4 waves) ----
  __shared__ float red[11];
  __shared__ float ctxsh[10];
  __shared__ float gsh[1024];
  __shared__ float hsh[H];
  __shared__ float etsh[16];
  for (int col = w; col < 11; col += 4) {
    const float4* pc = reinterpret_cast<const float4*>(p10 + col * NBLK);
    float v = 0.f;
#pragma unroll
    for (int i = 0; i < 4; ++i) {
      const float4 a = pc[lane + 64 * i];
      v += (a.x + a.y) + (a.z + a.w);
    }
    v = wave_reduce_sum(v);
    if (lane == 0) red[col] = v;
  }
  if (t < 10) etsh[t] = pitch_emb[tp_p[0] * 10 + t];
  __syncthreads();
  if (t < 10) ctxsh[t] = red[t] / red[10] + attn_b[t];
  __syncthreads();
#pragma unroll
  for (int i = 0; i < 4; ++i) {
    const int r = t + 256 * i;
    float g = ghh2[r];
#pragma unroll
    for (int c = 0; c < 10; ++c) g += WcT[c * NBLK + r] * ctxsh[c];
    gsh[r] = g;
  }
  __syncthreads();
  {
    const float i_s = 1.f / (1.f + __expf(-gsh[t]));
    const float f_s = 1.f / (1.f + __expf(-gsh[256 + t]));
    const float g_t = tanhf(gsh[512 + t]);
    const float o_s = 1.f / (1.f + __expf(-gsh[768 + t]));
    const float cn = f_s * c_in[t] + i_s * g_t;
    const float hn = o_s * tanhf(cn);
    out[79 + t] = hn;   // h_new at [79, 335)
    out[335 + t] = cn;  // c_new at [335, 591)
    hsh[t] = hn;
  }
  __syncthreads();
  const float4 h4 = reinterpret_cast<const float4*>(hsh)[lane];
  for (int row = w; row < 63; row += 4) {  // pitch head
    const float4 pw = reinterpret_cast<const float4*>(pitch_W + (size_t)row * H)[lane];
    float d = pw.x * h4.x + pw.y * h4.y + pw.z * h4.z + pw.w * h4.w;
    d = wave_reduce_sum(d);
    if (lane == 0) out[row] = d + pitch_b[row];
  }
  for (int row = w; row < 16; row += 4) {  // dur head (concat [e_true, h])
    const float* dw = dur_W + (size_t)row * 266;
    float d = 0.f;
    for (int k = lane; k < 266; k += 64)
      d += dw[k] * (k < 10 ? etsh[k] : hsh[k - 10]);
    d = wave_reduce_sum(d);
    if (lane == 0) out[63 + row] = d + dur_b[row];
  }
}

extern "C" void kernel_launch(void* const* d_in, const int* in_sizes, int n_in,
                              void* d_out, int out_size, void* d_ws, size_t ws_size,
                              hipStream_t stream) {
  const int* sec       = (const int*)d_in[0];
  const int* chord     = (const int*)d_in[1];
  const int* tp        = (const int*)d_in[2];
  const int* note      = (const int*)d_in[3];
  const float* hn      = (const float*)d_in[4];
  const float* cn      = (const float*)d_in[5];
  const float* E       = (const float*)d_in[6];
  const float* chord_e = (const float*)d_in[7];
  const float* pitch_e = (const float*)d_in[8];
  const float* dur_e   = (const float*)d_in[9];
  const float* W_ih    = (const float*)d_in[10];
  const float* W_hh    = (const float*)d_in[11];
  const float* b_ih    = (const float*)d_in[12];
  const float* b_hh    = (const float*)d_in[13];
  const float* pitch_W = (const float*)d_in[14];
  const float* pitch_b = (const float*)d_in[15];
  const float* dur_W   = (const float*)d_in[16];
  const float* dur_b   = (const float*)d_in[17];
  const float* attn_W  = (const float*)d_in[18];
  const float* attn_b  = (const float*)d_in[19];
  float* out = (float*)d_out;
  float* ws = (float*)d_ws;

  float* p10      = ws;               // 11 * 1024
  float* ghh2     = ws + 11 * NBLK;   // 1024
  float* WcT      = ghh2 + 1024;      // 10 * 1024
  float* dummy    = WcT + 10 * NBLK;  // 64
  unsigned* cnt   = (unsigned*)(dummy + 64);  // 1 (never reset; mod-1024 vote)

  k1_fused<<<NBLK, 256, 0, stream>>>(E, hn, attn_W, W_hh, b_ih, b_hh, W_ih,
                                     chord_e, pitch_e, dur_e, sec, chord, tp,
                                     note, attn_b, cn, pitch_W, pitch_b,
                                     dur_W, dur_b, p10, ghh2, WcT, dummy,
                                     cnt, out);
}